// Round 1
// 576.535 us; speedup vs baseline: 1.1341x; 1.1341x over previous
//
#include <hip/hip_runtime.h>
#include <math.h>

#define B_N 256
#define T_N 1024
#define D_N 128
#define H_N 256

// LDS strides in bf16 units; 16B-unit strides are ODD -> conflict-free b128.
#define SPS 120   // activations (15 x 16B)

// LDS map (shorts): activations only — weights are never staged anymore.
#define SP_OFF  0          // 64*120 = 7680
#define SQ_OFF  7680       // 7680
#define GUARD_OFF 15360    // 8 (zeroed; catches last-row K-overrun reads)
#define ACC_OFF 15368      // 512 shorts = 256 floats (byte off 30736, 16B aligned)
#define SMEM_SH 15880      // 31,760 B -> 4-5 blocks/CU by LDS

typedef __attribute__((ext_vector_type(8))) short short8;   // 8 bf16 = 4 VGPRs
typedef __attribute__((ext_vector_type(4))) float f32x4;

// ws layout (bf16 units): weights in MFMA *fragment order* so each B-fragment
// is ONE coalesced 1KB global_load_dwordx4 (lane i reads bytes [16i,16i+16)).
//   elem index within layer: ((nt*KR + k4)*64 + lane)*8 + j
//   holds WT[n = nt*16 + (lane&15)][k = k4*32 + (lane>>4)*8 + j], zero-padded.
#define WXT_OFF 0         // NT=16 KR=4 -> 32768
#define W1T_OFF 32768     // NT=7  KR=4 -> 14336
#define W2T_OFF 47104     // NT=7  KR=4 -> 14336   rows k>=100 ZERO
#define W3T_OFF 61440     // NT=7  KR=4 -> 14336
#define W4T_OFF 75776     // NT=4  KR=4 ->  8192
#define W5T_OFF 83968     // NT=16 KR=2 -> 16384   rows k>=50 zero
#define WT_TOTAL 100352

__device__ __forceinline__ float sigmoid_f(float z) {
    return 1.0f / (1.0f + __expf(-z));
}
__device__ __forceinline__ unsigned short f2bf(float f) {   // RNE fp32->bf16
    unsigned u = __float_as_uint(f);
    return (unsigned short)((u + 0x7FFFu + ((u >> 16) & 1u)) >> 16);
}

// ---- weight prep: fp32 W[K][N] -> bf16 fragment-ordered, zero-padded
__global__ __launch_bounds__(256) void prep_weights(
    const float* __restrict__ Wx, const float* __restrict__ W1,
    const float* __restrict__ W2, const float* __restrict__ W3,
    const float* __restrict__ W4, const float* __restrict__ W5,
    short* __restrict__ wt)
{
    int idx = blockIdx.x * 256 + threadIdx.x;
    if (idx >= WT_TOTAL) return;
    const float* src; int base, KR, K, N;
    if (idx < W1T_OFF)      { src = Wx; base = WXT_OFF; KR = 4; K = 128; N = 256; }
    else if (idx < W2T_OFF) { src = W1; base = W1T_OFF; KR = 4; K = 128; N = 100; }
    else if (idx < W3T_OFF) { src = W2; base = W2T_OFF; KR = 4; K = 100; N = 100; }
    else if (idx < W4T_OFF) { src = W3; base = W3T_OFF; KR = 4; K = 100; N = 100; }
    else if (idx < W5T_OFF) { src = W4; base = W4T_OFF; KR = 4; K = 100; N =  50; }
    else                    { src = W5; base = W5T_OFF; KR = 2; K =  50; N = 256; }
    int e    = idx - base;
    int j    = e & 7;
    int slot = e >> 3;            // (nt*KR + k4)*64 + lane
    int lane = slot & 63;
    int kk   = slot >> 6;         // nt*KR + k4
    int k4   = kk & (KR - 1);
    int nt   = kk / KR;
    int n = nt * 16 + (lane & 15);
    int k = k4 * 32 + (lane >> 4) * 8 + j;
    float v = (k < K && n < N) ? src[(size_t)k * N + n] : 0.0f;
    wt[idx] = (short)f2bf(v);
}

// A-fragment set (K=128): lane holds A[m=lr][k = k*32 + lq*8 + j]
template<int STRIDE>
__device__ __forceinline__ void loadA(const short* __restrict__ base, short8 (&a)[4],
                                      int mbase, int lr, int lq)
{
    #pragma unroll
    for (int k = 0; k < 4; ++k)
        a[k] = *reinterpret_cast<const short8*>(&base[(mbase + lr) * STRIDE + k * 32 + lq * 8]);
}

// Dense layer: A in regs, B straight from GLOBAL (fragment-ordered, coalesced,
// L1/L2-hot), relu, bf16 store of own rows (wave-local -> NO barrier needed).
// C/D layout: row = lq*4+r, col = n0+lr (verified m89/m91).
template<int NT, int OUTS>
__device__ __forceinline__ void denseLG(const short8 (&a)[4], const short* __restrict__ gW,
                                        const float* __restrict__ bias, int ncap,
                                        short* __restrict__ dst, int mbase, int lr, int lq,
                                        int lane)
{
    #pragma unroll 2
    for (int nt = 0; nt < NT; ++nt) {
        const int n0 = nt * 16;
        f32x4 acc = {0.f, 0.f, 0.f, 0.f};
        #pragma unroll
        for (int k = 0; k < 4; ++k) {
            const short8 bf = *reinterpret_cast<const short8*>(&gW[((nt * 4 + k) * 64 + lane) * 8]);
            acc = __builtin_amdgcn_mfma_f32_16x16x32_bf16(a[k], bf, acc, 0, 0, 0);
        }
        const bool valid = (n0 + lr < ncap);
        const float bv = valid ? bias[n0 + lr] : 0.0f;
        #pragma unroll
        for (int r = 0; r < 4; ++r) {
            float v = valid ? fmaxf(acc[r] + bv, 0.0f) : 0.0f;
            dst[(mbase + lq * 4 + r) * OUTS + n0 + lr] = (short)f2bf(v);
        }
    }
}

// Fused MLP + linearized scan (relu is identity in scan: gate>0, hidden0=0):
//   hidden[b,h] = sum_t gate[t,b,(h - s*(T-1-t)) mod H]
// Grid 4096 = 16 t-segments x 256 batch; block = 4 waves x 16 t-rows.
// Weights read per-fragment from global (L1/L2-resident, all waves share) —
// only 2 barriers per block (post-zero, pre-flush); waves otherwise independent.
__global__ __launch_bounds__(256, 4) void srnn_gate_scan(
    const float* __restrict__ x, const short* __restrict__ wt,
    const float* __restrict__ bx, const float* __restrict__ b1,
    const float* __restrict__ b2, const float* __restrict__ b3,
    const float* __restrict__ b4, const float* __restrict__ b5,
    const int* __restrict__ shiftp,
    float* __restrict__ out)   // out[0..255]=output, out[256..]=hidden (pre-zeroed)
{
    __shared__ __align__(16) short smem[SMEM_SH];
    short* sP = smem + SP_OFF;
    short* sQ = smem + SQ_OFF;
    float* accum = reinterpret_cast<float*>(smem + ACC_OFF);

    const int tid  = threadIdx.x;
    const int b    = blockIdx.x & 255;
    const int seg  = blockIdx.x >> 8;      // 0..15
    const int lane = tid & 63;
    const int mbase = (tid >> 6) * 16;     // wave's row base in LDS
    const int lr = lane & 15;              // A m-index / B n-index / C-D col
    const int lq = lane >> 4;              // quad; C/D row = lq*4+r
    const int s  = *shiftp;
    const int tw0 = seg * 64 + mbase;      // t of this wave's row 0

    // zero ALL of LDS: act pads + guard finite (K-overrun reads hit zero or
    // finite bf16 acts of a neighbor wave — benign: W rows k>=K are zero),
    // accum zeroed for atomics.
    {
        const float4 z = {0.f, 0.f, 0.f, 0.f};
        float4* dst = reinterpret_cast<float4*>(smem);
        #pragma unroll
        for (int i = 0; i < 8; ++i) {
            int sl = tid + i * 256;
            if (sl < SMEM_SH / 8) dst[sl] = z;
        }
    }

    // x A-fragments straight from global: A layout wants row=lr per lane, which
    // matches per-lane row reads. 2x float4 per k-reg, f2bf in regs.
    short8 ax4[4];
    {
        const float* xr = x + ((size_t)b * T_N + tw0 + lr) * D_N;
        #pragma unroll
        for (int k = 0; k < 4; ++k) {
            const float4 v0 = *reinterpret_cast<const float4*>(&xr[k * 32 + lq * 8]);
            const float4 v1 = *reinterpret_cast<const float4*>(&xr[k * 32 + lq * 8 + 4]);
            short8 t;
            t[0] = (short)f2bf(v0.x); t[1] = (short)f2bf(v0.y);
            t[2] = (short)f2bf(v0.z); t[3] = (short)f2bf(v0.w);
            t[4] = (short)f2bf(v1.x); t[5] = (short)f2bf(v1.y);
            t[6] = (short)f2bf(v1.z); t[7] = (short)f2bf(v1.w);
            ax4[k] = t;
        }
    }
    __syncthreads();                       // zero-init visible to all waves

    // ---- MLP chain, zero barriers: activations are wave-local rows; DS ops
    // from one wave complete in order (write->read of own rows is safe).
    short8 aL[4];
    denseLG<7, SPS>(ax4, wt + W1T_OFF, b1, 100, sP, mbase, lr, lq, lane);
    loadA<SPS>(sP, aL, mbase, lr, lq);
    denseLG<7, SPS>(aL, wt + W2T_OFF, b2, 100, sQ, mbase, lr, lq, lane);
    loadA<SPS>(sQ, aL, mbase, lr, lq);
    denseLG<7, SPS>(aL, wt + W3T_OFF, b3, 100, sP, mbase, lr, lq, lane);
    loadA<SPS>(sP, aL, mbase, lr, lq);
    denseLG<4, SPS>(aL, wt + W4T_OFF, b4, 50, sQ, mbase, lr, lq, lane);

    // L4 output as K=64 A-fragments for L5 (cols 50..63 are zeros from ncap)
    short8 c0 = *reinterpret_cast<const short8*>(&sQ[(mbase + lr) * SPS + 0 + lq * 8]);
    short8 c1 = *reinterpret_cast<const short8*>(&sQ[(mbase + lr) * SPS + 32 + lq * 8]);

    // ---- tail: Lx (A=ax4) + L5 (A=c0/c1) + gate + scatter over all 16 n-tiles
    const short* gWx = wt + WXT_OFF;
    const short* gW5 = wt + W5T_OFF;
    #pragma unroll 2
    for (int ntl = 0; ntl < 16; ++ntl) {
        const int n0 = ntl * 16;
        f32x4 axv = {0.f, 0.f, 0.f, 0.f};
        #pragma unroll
        for (int k = 0; k < 4; ++k) {
            const short8 bf = *reinterpret_cast<const short8*>(&gWx[((ntl * 4 + k) * 64 + lane) * 8]);
            axv = __builtin_amdgcn_mfma_f32_16x16x32_bf16(ax4[k], bf, axv, 0, 0, 0);
        }
        f32x4 a5v = {0.f, 0.f, 0.f, 0.f};
        {
            const short8 bf0 = *reinterpret_cast<const short8*>(&gW5[((ntl * 2 + 0) * 64 + lane) * 8]);
            const short8 bf1 = *reinterpret_cast<const short8*>(&gW5[((ntl * 2 + 1) * 64 + lane) * 8]);
            a5v = __builtin_amdgcn_mfma_f32_16x16x32_bf16(c0, bf0, a5v, 0, 0, 0);
            a5v = __builtin_amdgcn_mfma_f32_16x16x32_bf16(c1, bf1, a5v, 0, 0, 0);
        }
        const float bxv = bx[n0 + lr];
        const float b5v = b5[n0 + lr];
        #pragma unroll
        for (int r = 0; r < 4; ++r) {
            const int t = tw0 + lq * 4 + r;
            const float g = sigmoid_f(a5v[r] + b5v) * sigmoid_f(axv[r] + bxv);
            int v = n0 + lr + s * (T_N - 1 - t);
            v %= H_N; if (v < 0) v += H_N;
            atomicAdd(&accum[v], g);   // per-t the h-map is a bijection
        }
    }
    __syncthreads();

    // flush partial hidden (16 segment-blocks per b -> global atomic, out zeroed)
    atomicAdd(&out[256 + b * 256 + tid], accum[tid]);
}

// output[b] = sigmoid(hidden[b,:] @ Wo + bo)
__global__ __launch_bounds__(256) void srnn_output(
    const float* __restrict__ Wo, const float* __restrict__ bo,
    float* __restrict__ out)
{
    __shared__ float red[256];
    const int b = blockIdx.x, tid = threadIdx.x;
    red[tid] = out[256 + b * 256 + tid] * Wo[tid];
    __syncthreads();
    #pragma unroll
    for (int off = 128; off > 0; off >>= 1) {
        if (tid < off) red[tid] += red[tid + off];
        __syncthreads();
    }
    if (tid == 0) out[b] = sigmoid_f(red[0] + bo[0]);
}

extern "C" void kernel_launch(void* const* d_in, const int* in_sizes, int n_in,
                              void* d_out, int out_size, void* d_ws, size_t ws_size,
                              hipStream_t stream)
{
    const float* x  = (const float*)d_in[0];
    const float* Wx = (const float*)d_in[1];
    const float* bx = (const float*)d_in[2];
    const float* W1 = (const float*)d_in[3];
    const float* b1 = (const float*)d_in[4];
    const float* W2 = (const float*)d_in[5];
    const float* b2 = (const float*)d_in[6];
    const float* W3 = (const float*)d_in[7];
    const float* b3 = (const float*)d_in[8];
    const float* W4 = (const float*)d_in[9];
    const float* b4 = (const float*)d_in[10];
    const float* W5 = (const float*)d_in[11];
    const float* b5 = (const float*)d_in[12];
    const float* Wo = (const float*)d_in[13];
    const float* bo = (const float*)d_in[14];
    const int* shiftp = (const int*)d_in[15];
    float* out = (float*)d_out;
    short* wt  = (short*)d_ws;   // 200,704 B scratch: bf16 fragment-ordered weights

    // hidden accumulated with atomics -> zero-init (d_out is poisoned)
    hipMemsetAsync(d_out, 0, (size_t)out_size * sizeof(float), stream);

    prep_weights<<<dim3((WT_TOTAL + 255) / 256), dim3(256), 0, stream>>>(
        Wx, W1, W2, W3, W4, W5, wt);
    srnn_gate_scan<<<dim3(4096), dim3(256), 0, stream>>>(
        x, wt, bx, b1, b2, b3, b4, b5, shiftp, out);
    srnn_output<<<dim3(256), dim3(256), 0, stream>>>(Wo, bo, out);
}